// Round 12
// baseline (118.894 us; speedup 1.0000x reference)
//
#include <hip/hip_runtime.h>
#include <cmath>

#define DD 128
#define LOG2E 1.4426950408889634f
// Upper-bound margin for the level-2 LSE stabilizer: v1 <= colmax0 + b*ln(64).
// LSE is exact for ANY stabilizer M; overshoot <=4.16 costs <=~24 bits of term
// scale - no underflow vs the 1e-35 clamp.
#define MMARGIN 4.16f

__device__ __forceinline__ float sigm(float x) { return 1.0f / (1.0f + __expf(-x)); }

// Async global->LDS stage: 16B/lane, per-lane global src, wave-uniform LDS dest.
// No VGPR cost (the whole point: the 64-VGPR allocator cap killed every
// register-prefetch attempt - R1 sink, R2/R7 spill). Tracked by vmcnt.
#define STAGE(GP, LP)                                                     \
    __builtin_amdgcn_global_load_lds(                                     \
        (__attribute__((address_space(1))) void*)(GP),                    \
        (__attribute__((address_space(3))) void*)(LP), 16, 0, 0)

// Level-1, R32 (= R26/R31 verbatim, ~10us): 512 blocks, surrogate colmax bound.
__global__ __launch_bounds__(512, 4)
void k_lvl1(const float* __restrict__ mu_min0, const float* __restrict__ mu_max0,
            const float* __restrict__ braw_min, const float* __restrict__ braw_max,
            const float* __restrict__ adj0, const float* __restrict__ u0,
            float* __restrict__ out,
            float2* __restrict__ mu2_1, float2* __restrict__ bb2_1,
            float4* __restrict__ pmaxf) {
    __shared__ float wsh[64];
    __shared__ int npres;
    __shared__ float4 red[8][64];
    __shared__ float4 cmx[8][64];
    __shared__ float4 carrA[64], carrB[64];
    const int tid = threadIdx.x;
    const int w = tid >> 6, lane = tid & 63;
    const int c = blockIdx.x;

    if (tid < 16) {
        int i = blockIdx.x * 16 + tid;
        out[i] = mu_min0[i];
        out[8192 + i] = mu_max0[i];
        out[16384 + i] = sigm(braw_min[i]) + 1e-6f;
        out[24576 + i] = sigm(braw_max[i]) + 1e-6f;
    }

    if (tid < 64) {
        int idx = c * 64 + tid;
        float uu = u0[idx] + 1e-10f;
        float g = -__logf(-__logf(uu) + 1e-10f);
        bool pres = (adj0[idx] + g) > 0.0f;
        wsh[tid] = pres ? 1.0f : 1e-10f;
        unsigned long long m = __ballot(pres);
        if (tid == 0) npres = (int)__popcll(m);
    }
    __syncthreads();

    const int p0 = w * 8;
    const int dbase = 2 * lane;

    float4 accB = make_float4(0.f, 0.f, 0.f, 0.f);
    float4 mrow[8];
    float wreg[8];
    float cm_mn0 = -INFINITY, cm_mn1 = -INFINITY, cm_ng0 = -INFINITY, cm_ng1 = -INFINITY;
    #pragma unroll
    for (int z = 0; z < 8; ++z) {
        int p = p0 + z;
        float2 bmr = *(const float2*)(braw_min + p * DD + dbase);
        float2 bxr = *(const float2*)(braw_max + p * DD + dbase);
        float2 mnr = *(const float2*)(mu_min0 + p * DD + dbase);
        float2 mxr = *(const float2*)(mu_max0 + p * DD + dbase);
        float bm0 = sigm(bmr.x) + 1e-6f, bm1 = sigm(bmr.y) + 1e-6f;
        float bx0 = sigm(bxr.x) + 1e-6f, bx1 = sigm(bxr.y) + 1e-6f;
        mrow[z] = make_float4(mnr.x, mxr.x, mnr.y, mxr.y);
        cm_mn0 = fmaxf(cm_mn0, mnr.x); cm_mn1 = fmaxf(cm_mn1, mnr.y);
        cm_ng0 = fmaxf(cm_ng0, -mxr.x); cm_ng1 = fmaxf(cm_ng1, -mxr.y);
        float wv = wsh[p];
        wreg[z] = wv;
        accB.x = fmaf(wv, bm0, accB.x);
        accB.y = fmaf(wv, bx0, accB.y);
        accB.z = fmaf(wv, bm1, accB.z);
        accB.w = fmaf(wv, bx1, accB.w);
    }
    red[w][lane] = accB;
    cmx[w][lane] = make_float4(cm_mn0, cm_ng0, cm_mn1, cm_ng1);
    __syncthreads();

    float bmin0, bmax0, bmin1, bmax1, rmin0, rmin1, nrmax0, nrmax1, Mm0, Mm1, Mg0, Mg1;
    if (tid < 64) {
        float4 S = red[0][lane];
        float4 M = cmx[0][lane];
        #pragma unroll
        for (int ww = 1; ww < 8; ++ww) {
            float4 t = red[ww][lane];
            S.x += t.x; S.y += t.y; S.z += t.z; S.w += t.w;
            float4 m = cmx[ww][lane];
            M.x = fmaxf(M.x, m.x); M.y = fmaxf(M.y, m.y);
            M.z = fmaxf(M.z, m.z); M.w = fmaxf(M.w, m.w);
        }
        Mm0 = M.x; Mg0 = M.y; Mm1 = M.z; Mg1 = M.w;
        if (c == 0) {
            pmaxf[lane] = make_float4(Mm0 + MMARGIN, Mg0 + MMARGIN,
                                      Mm1 + MMARGIN, Mg1 + MMARGIN);
        }
        const float wsv = (float)npres + 1e-10f;
        bmin0 = S.x / wsv; bmax0 = S.y / wsv; bmin1 = S.z / wsv; bmax1 = S.w / wsv;
        rmin0 = 1.0f / fmaxf(bmin0, 1e-30f);
        rmin1 = 1.0f / fmaxf(bmin1, 1e-30f);
        nrmax0 = -1.0f / fmaxf(bmax0, 1e-30f);
        nrmax1 = -1.0f / fmaxf(bmax1, 1e-30f);
        float rm20 = rmin0 * LOG2E, rm21 = rmin1 * LOG2E;
        float nx20 = nrmax0 * LOG2E, nx21 = nrmax1 * LOG2E;
        carrA[lane] = make_float4(rm20, rm21, nx20, nx21);
        carrB[lane] = make_float4(-rm20 * Mm0, -rm21 * Mm1, nx20 * Mg0, nx21 * Mg1);
    }
    __syncthreads();

    float4 cA = carrA[lane], cB = carrB[lane];

    float4 accS = make_float4(0.f, 0.f, 0.f, 0.f);
    #pragma unroll
    for (int z = 0; z < 8; ++z) {
        float4 q = mrow[z];
        float wv = wreg[z];
        accS.x = fmaf(wv, __builtin_amdgcn_exp2f(fmaf(q.x, cA.x, cB.x)), accS.x);
        accS.y = fmaf(wv, __builtin_amdgcn_exp2f(fmaf(q.y, cA.z, cB.z)), accS.y);
        accS.z = fmaf(wv, __builtin_amdgcn_exp2f(fmaf(q.z, cA.y, cB.y)), accS.z);
        accS.w = fmaf(wv, __builtin_amdgcn_exp2f(fmaf(q.w, cA.w, cB.w)), accS.w);
    }
    red[w][lane] = accS;
    __syncthreads();

    if (tid < 64) {
        float4 S = red[0][lane];
        #pragma unroll
        for (int ww = 1; ww < 8; ++ww) {
            float4 t = red[ww][lane];
            S.x += t.x; S.y += t.y; S.z += t.z; S.w += t.w;
        }
        const float S10 = fmaxf(S.x, 1e-35f);
        const float S20 = fmaxf(S.y, 1e-35f);
        const float S11 = fmaxf(S.z, 1e-35f);
        const float S21 = fmaxf(S.w, 1e-35f);
        const int idx = c * DD + 2 * lane;
        float v10 = bmin0 * fmaf(rmin0, Mm0, __logf(S10));
        float v11 = bmin1 * fmaf(rmin1, Mm1, __logf(S11));
        float v20 = -bmax0 * fmaf(-nrmax0, Mg0, __logf(S20));
        float v21 = -bmax1 * fmaf(-nrmax1, Mg1, __logf(S21));
        *(float2*)(out + 32768 + idx)  = make_float2(v10, v11);
        *(float2*)(out + 98304 + idx)  = make_float2(v20, v21);
        *(float2*)(out + 163840 + idx) = make_float2(bmin0, bmin1);
        *(float2*)(out + 229376 + idx) = make_float2(bmax0, bmax1);
        *(float4*)(mu2_1 + idx) = make_float4(v10, v20, v11, v21);
        *(float4*)(bb2_1 + idx) = make_float4(bmin0, bmax0, bmin1, bmax1);
    }
}

// Level-2 DENSE, R32: R31 body + async LDS staging of the row streams.
// Per wave: 4 slots x 1KB in an arena ALIASED onto red[w] (exact 4KB match).
// Loop (no barriers - staging is wave-private): vmcnt(2) -> ds_read 2 rows ->
// fmaf -> lgkmcnt(0) (slots retired) -> STAGE rows z+4,z+5 into freed slots.
// Counted vmcnt never drains to 0 mid-loop (T3/T4); last iter waits vmcnt(0),
// so red[w] writes after the loop are safe; the carr barrier orders red reads
// before mu-pass restaging. Zero VGPR cost -> allocator has nothing to spill.
__global__ __launch_bounds__(512, 4)
void k_level2d(const float* __restrict__ logits, const float* __restrict__ u,
               const float2* __restrict__ bb2, const float2* __restrict__ mu2,
               const float4* __restrict__ pmaxf,
               float* __restrict__ o_mu_min, float* __restrict__ o_mu_max,
               float* __restrict__ o_b_min, float* __restrict__ o_b_max) {
    constexpr int P = 512, TC = 4;
    __shared__ __align__(16) float wsh[P][TC];
    __shared__ int npres[TC];
    __shared__ __align__(16) char redarena[32768];   // red[8][TC][64] float4 == arena
    __shared__ float4 carrA[TC][64], carrB[TC][64];
    float4 (*red)[TC][64] = (float4(*)[TC][64])redarena;
    const int tid = threadIdx.x;
    const int w = tid >> 6;
    const int lane = tid & 63;
    const int c0 = blockIdx.x * TC;
    if (tid < TC) npres[tid] = 0;
    __syncthreads();

    #pragma unroll
    for (int it = 0; it < TC; ++it) {
        int idx = (c0 + it) * P + tid;
        float uu = u[idx] + 1e-10f;
        float g = -__logf(-__logf(uu) + 1e-10f);
        bool pres = (logits[idx] + g) > 0.0f;
        wsh[tid][it] = pres ? 1.0f : 1e-10f;
        unsigned long long m = __ballot(pres);
        if (lane == 0) atomicAdd(&npres[it], (int)__popcll(m));
    }
    __syncthreads();   // drains gumbel vmcnt: loop-start outstanding = stages only

    const unsigned lb = (unsigned)(lane << 4);
    const char* bbc = (const char*)bb2 + (unsigned)(w * 64) * 1024u + lb;
    const char* muc = (const char*)mu2 + (unsigned)(w * 64) * 1024u + lb;
    const int p0 = w * 64;
    char* arena = redarena + (w << 12);   // wave-private 4KB = red[w]

    // ---------------- pass 1: weighted beta sums (LDS-staged stream) ------------
    float4 accB[TC];
    #pragma unroll
    for (int j = 0; j < TC; ++j) accB[j] = make_float4(0.f, 0.f, 0.f, 0.f);

    STAGE(bbc + 0u,    arena);
    STAGE(bbc + 1024u, arena + 1024);
    STAGE(bbc + 2048u, arena + 2048);
    STAGE(bbc + 3072u, arena + 3072);
    for (int z = 0; z < 64; z += 2) {
        if (z < 62) { asm volatile("s_waitcnt vmcnt(2)" ::: "memory"); }
        else        { asm volatile("s_waitcnt vmcnt(0)" ::: "memory"); }
        __builtin_amdgcn_sched_barrier(0);
        float4 q0 = *(const float4*)(arena + ((z & 3) << 10) + lb);
        float4 q1 = *(const float4*)(arena + (((z + 1) & 3) << 10) + lb);
        float4 w0 = *(const float4*)wsh[p0 + z + 0];
        float4 w1 = *(const float4*)wsh[p0 + z + 1];
        const float* wf0 = (const float*)&w0;
        const float* wf1 = (const float*)&w1;
        #pragma unroll
        for (int j = 0; j < TC; ++j) {
            accB[j].x = fmaf(wf0[j], q0.x, accB[j].x);
            accB[j].y = fmaf(wf0[j], q0.y, accB[j].y);
            accB[j].z = fmaf(wf0[j], q0.z, accB[j].z);
            accB[j].w = fmaf(wf0[j], q0.w, accB[j].w);
        }
        #pragma unroll
        for (int j = 0; j < TC; ++j) {
            accB[j].x = fmaf(wf1[j], q1.x, accB[j].x);
            accB[j].y = fmaf(wf1[j], q1.y, accB[j].y);
            accB[j].z = fmaf(wf1[j], q1.z, accB[j].z);
            accB[j].w = fmaf(wf1[j], q1.w, accB[j].w);
        }
        asm volatile("s_waitcnt lgkmcnt(0)" ::: "memory");   // slots retired
        __builtin_amdgcn_sched_barrier(0);
        if (z + 4 < 64) {
            STAGE(bbc + (unsigned)(z + 4) * 1024u, arena + ((z & 3) << 10));
            STAGE(bbc + (unsigned)(z + 5) * 1024u, arena + (((z + 1) & 3) << 10));
        }
    }
    #pragma unroll
    for (int j = 0; j < TC; ++j) red[w][j][lane] = accB[j];
    __syncthreads();

    float bmin0, bmax0, bmin1, bmax1, rmin0, rmin1, nrmax0, nrmax1, Mm0, Mm1, Mg0, Mg1;
    const int rj = tid >> 6;
    if (tid < 256) {
        float4 S = red[0][rj][lane];
        #pragma unroll
        for (int ww = 1; ww < 8; ++ww) {
            float4 t = red[ww][rj][lane];
            S.x += t.x; S.y += t.y; S.z += t.z; S.w += t.w;
        }
        float4 km = pmaxf[lane];
        Mm0 = km.x; Mg0 = km.y; Mm1 = km.z; Mg1 = km.w;
        const float wsv = (float)npres[rj] + 1e-10f;
        bmin0 = S.x / wsv; bmax0 = S.y / wsv; bmin1 = S.z / wsv; bmax1 = S.w / wsv;
        rmin0 = 1.0f / fmaxf(bmin0, 1e-30f);
        rmin1 = 1.0f / fmaxf(bmin1, 1e-30f);
        nrmax0 = -1.0f / fmaxf(bmax0, 1e-30f);
        nrmax1 = -1.0f / fmaxf(bmax1, 1e-30f);
        float rm20 = rmin0 * LOG2E, rm21 = rmin1 * LOG2E;
        float nx20 = nrmax0 * LOG2E, nx21 = nrmax1 * LOG2E;
        carrA[rj][lane] = make_float4(rm20, rm21, nx20, nx21);
        carrB[rj][lane] = make_float4(-rm20 * Mm0, -rm21 * Mm1, nx20 * Mg0, nx21 * Mg1);
    }
    __syncthreads();   // all red reads done -> arena reusable for mu staging

    float4 cA[TC], cB[TC];
    #pragma unroll
    for (int j = 0; j < TC; ++j) { cA[j] = carrA[j][lane]; cB[j] = carrB[j][lane]; }

    // ---------------- pass 2: exp accumulation (LDS-staged stream) --------------
    float4 accS[TC];
    #pragma unroll
    for (int j = 0; j < TC; ++j) accS[j] = make_float4(0.f, 0.f, 0.f, 0.f);

    STAGE(muc + 0u,    arena);
    STAGE(muc + 1024u, arena + 1024);
    STAGE(muc + 2048u, arena + 2048);
    STAGE(muc + 3072u, arena + 3072);
    for (int z = 0; z < 64; z += 2) {
        if (z < 62) { asm volatile("s_waitcnt vmcnt(2)" ::: "memory"); }
        else        { asm volatile("s_waitcnt vmcnt(0)" ::: "memory"); }
        __builtin_amdgcn_sched_barrier(0);
        float4 q0 = *(const float4*)(arena + ((z & 3) << 10) + lb);
        float4 q1 = *(const float4*)(arena + (((z + 1) & 3) << 10) + lb);
        float4 w0 = *(const float4*)wsh[p0 + z + 0];
        float4 w1 = *(const float4*)wsh[p0 + z + 1];
        const float* wf0 = (const float*)&w0;
        const float* wf1 = (const float*)&w1;
        #pragma unroll
        for (int j = 0; j < TC; ++j) {
            if (wf0[j] > 0.5f) {
                accS[j].x += __builtin_amdgcn_exp2f(fmaf(q0.x, cA[j].x, cB[j].x));
                accS[j].y += __builtin_amdgcn_exp2f(fmaf(q0.y, cA[j].z, cB[j].z));
                accS[j].z += __builtin_amdgcn_exp2f(fmaf(q0.z, cA[j].y, cB[j].y));
                accS[j].w += __builtin_amdgcn_exp2f(fmaf(q0.w, cA[j].w, cB[j].w));
            }
            if (wf1[j] > 0.5f) {
                accS[j].x += __builtin_amdgcn_exp2f(fmaf(q1.x, cA[j].x, cB[j].x));
                accS[j].y += __builtin_amdgcn_exp2f(fmaf(q1.y, cA[j].z, cB[j].z));
                accS[j].z += __builtin_amdgcn_exp2f(fmaf(q1.z, cA[j].y, cB[j].y));
                accS[j].w += __builtin_amdgcn_exp2f(fmaf(q1.w, cA[j].w, cB[j].w));
            }
        }
        asm volatile("s_waitcnt lgkmcnt(0)" ::: "memory");
        __builtin_amdgcn_sched_barrier(0);
        if (z + 4 < 64) {
            STAGE(muc + (unsigned)(z + 4) * 1024u, arena + ((z & 3) << 10));
            STAGE(muc + (unsigned)(z + 5) * 1024u, arena + (((z + 1) & 3) << 10));
        }
    }
    #pragma unroll
    for (int j = 0; j < TC; ++j) red[w][j][lane] = accS[j];
    __syncthreads();

    if (tid < 256) {
        float4 S = red[0][rj][lane];
        #pragma unroll
        for (int ww = 1; ww < 8; ++ww) {
            float4 t = red[ww][rj][lane];
            S.x += t.x; S.y += t.y; S.z += t.z; S.w += t.w;
        }
        const float S10 = fmaxf(S.x, 1e-35f);
        const float S20 = fmaxf(S.y, 1e-35f);
        const float S11 = fmaxf(S.z, 1e-35f);
        const float S21 = fmaxf(S.w, 1e-35f);
        const int idx = (c0 + rj) * DD + 2 * lane;
        float v10 = bmin0 * fmaf(rmin0, Mm0, __logf(S10));
        float v11 = bmin1 * fmaf(rmin1, Mm1, __logf(S11));
        float v20 = -bmax0 * fmaf(-nrmax0, Mg0, __logf(S20));
        float v21 = -bmax1 * fmaf(-nrmax1, Mg1, __logf(S21));
        *(float2*)(o_mu_min + idx) = make_float2(v10, v11);
        *(float2*)(o_mu_max + idx) = make_float2(v20, v21);
        *(float2*)(o_b_min + idx)  = make_float2(bmin0, bmin1);
        *(float2*)(o_b_max + idx)  = make_float2(bmax0, bmax1);
    }
}

extern "C" void kernel_launch(void* const* d_in, const int* in_sizes, int n_in,
                              void* d_out, int out_size, void* d_ws, size_t ws_size,
                              hipStream_t stream) {
    const float* mu_min0  = (const float*)d_in[0];
    const float* mu_max0  = (const float*)d_in[1];
    const float* braw_min = (const float*)d_in[2];
    const float* braw_max = (const float*)d_in[3];
    const float* adj0     = (const float*)d_in[4];   // (512, 64)
    const float* adj1     = (const float*)d_in[5];   // (2048, 512)
    const float* u0       = (const float*)d_in[6];   // (1, 512, 64)
    const float* u1       = (const float*)d_in[7];   // (1, 2048, 512)
    float* out = (float*)d_out;
    float* ws = (float*)d_ws;

    float4* pmaxf = (float4*)ws;                    // 64 float4 = 1 KB
    float2* mu2_1 = (float2*)(ws + 256);            // 512*128 float2 = 512 KB
    float2* bb2_1 = mu2_1 + 512 * DD;               // 512 KB

    // out offsets (f32): 0:mu_min0 8192:mu_max0 16384:bmin0 24576:bmax0
    // 32768:mu_min1 98304:mu_max1 163840:b_min1 229376:b_max1 (each 65536)
    // 294912:mu_min2 557056:mu_max2 819200:b_min2 1081344:b_max2 (each 262144)

    k_lvl1<<<dim3(512), dim3(512), 0, stream>>>(
        mu_min0, mu_max0, braw_min, braw_max, adj0, u0,
        out, mu2_1, bb2_1, pmaxf);

    k_level2d<<<dim3(512), dim3(512), 0, stream>>>(
        adj1, u1, bb2_1, mu2_1, pmaxf,
        out + 294912, out + 557056, out + 819200, out + 1081344);
}

// Round 13
// 113.423 us; speedup vs baseline: 1.0482x; 1.0482x over previous
//
#include <hip/hip_runtime.h>
#include <cmath>

#define DD 128
#define LOG2E 1.4426950408889634f
// Upper-bound margin for the level-2 LSE stabilizer: v1 <= colmax0 + b*ln(64).
// LSE is exact for ANY stabilizer M; overshoot <=4.16 costs <=~24 bits of term
// scale - no underflow vs the 1e-35 clamp.
#define MMARGIN 4.16f

__device__ __forceinline__ float sigm(float x) { return 1.0f / (1.0f + __expf(-x)); }

// Level-1, R33 (= R31 verbatim): 512 blocks, surrogate colmax bound stored by
// block 0 as a plain 1KB write. Closed axes: atomics (R24/R25), cooperative
// fusion (R10, not graph-capturable).
__global__ __launch_bounds__(512, 4)
void k_lvl1(const float* __restrict__ mu_min0, const float* __restrict__ mu_max0,
            const float* __restrict__ braw_min, const float* __restrict__ braw_max,
            const float* __restrict__ adj0, const float* __restrict__ u0,
            float* __restrict__ out,
            float2* __restrict__ mu2_1, float2* __restrict__ bb2_1,
            float4* __restrict__ pmaxf) {
    __shared__ float wsh[64];
    __shared__ int npres;
    __shared__ float4 red[8][64];
    __shared__ float4 cmx[8][64];
    __shared__ float4 carrA[64], carrB[64];
    const int tid = threadIdx.x;
    const int w = tid >> 6, lane = tid & 63;
    const int c = blockIdx.x;

    if (tid < 16) {
        int i = blockIdx.x * 16 + tid;
        out[i] = mu_min0[i];
        out[8192 + i] = mu_max0[i];
        out[16384 + i] = sigm(braw_min[i]) + 1e-6f;
        out[24576 + i] = sigm(braw_max[i]) + 1e-6f;
    }

    if (tid < 64) {
        int idx = c * 64 + tid;
        float uu = u0[idx] + 1e-10f;
        float g = -__logf(-__logf(uu) + 1e-10f);
        bool pres = (adj0[idx] + g) > 0.0f;
        wsh[tid] = pres ? 1.0f : 1e-10f;
        unsigned long long m = __ballot(pres);
        if (tid == 0) npres = (int)__popcll(m);
    }
    __syncthreads();

    const int p0 = w * 8;
    const int dbase = 2 * lane;

    float4 accB = make_float4(0.f, 0.f, 0.f, 0.f);
    float4 mrow[8];
    float wreg[8];
    float cm_mn0 = -INFINITY, cm_mn1 = -INFINITY, cm_ng0 = -INFINITY, cm_ng1 = -INFINITY;
    #pragma unroll
    for (int z = 0; z < 8; ++z) {
        int p = p0 + z;
        float2 bmr = *(const float2*)(braw_min + p * DD + dbase);
        float2 bxr = *(const float2*)(braw_max + p * DD + dbase);
        float2 mnr = *(const float2*)(mu_min0 + p * DD + dbase);
        float2 mxr = *(const float2*)(mu_max0 + p * DD + dbase);
        float bm0 = sigm(bmr.x) + 1e-6f, bm1 = sigm(bmr.y) + 1e-6f;
        float bx0 = sigm(bxr.x) + 1e-6f, bx1 = sigm(bxr.y) + 1e-6f;
        mrow[z] = make_float4(mnr.x, mxr.x, mnr.y, mxr.y);
        cm_mn0 = fmaxf(cm_mn0, mnr.x); cm_mn1 = fmaxf(cm_mn1, mnr.y);
        cm_ng0 = fmaxf(cm_ng0, -mxr.x); cm_ng1 = fmaxf(cm_ng1, -mxr.y);
        float wv = wsh[p];
        wreg[z] = wv;
        accB.x = fmaf(wv, bm0, accB.x);
        accB.y = fmaf(wv, bx0, accB.y);
        accB.z = fmaf(wv, bm1, accB.z);
        accB.w = fmaf(wv, bx1, accB.w);
    }
    red[w][lane] = accB;
    cmx[w][lane] = make_float4(cm_mn0, cm_ng0, cm_mn1, cm_ng1);
    __syncthreads();

    float bmin0, bmax0, bmin1, bmax1, rmin0, rmin1, nrmax0, nrmax1, Mm0, Mm1, Mg0, Mg1;
    if (tid < 64) {
        float4 S = red[0][lane];
        float4 M = cmx[0][lane];
        #pragma unroll
        for (int ww = 1; ww < 8; ++ww) {
            float4 t = red[ww][lane];
            S.x += t.x; S.y += t.y; S.z += t.z; S.w += t.w;
            float4 m = cmx[ww][lane];
            M.x = fmaxf(M.x, m.x); M.y = fmaxf(M.y, m.y);
            M.z = fmaxf(M.z, m.z); M.w = fmaxf(M.w, m.w);
        }
        Mm0 = M.x; Mg0 = M.y; Mm1 = M.z; Mg1 = M.w;
        if (c == 0) {
            pmaxf[lane] = make_float4(Mm0 + MMARGIN, Mg0 + MMARGIN,
                                      Mm1 + MMARGIN, Mg1 + MMARGIN);
        }
        const float wsv = (float)npres + 1e-10f;
        bmin0 = S.x / wsv; bmax0 = S.y / wsv; bmin1 = S.z / wsv; bmax1 = S.w / wsv;
        rmin0 = 1.0f / fmaxf(bmin0, 1e-30f);
        rmin1 = 1.0f / fmaxf(bmin1, 1e-30f);
        nrmax0 = -1.0f / fmaxf(bmax0, 1e-30f);
        nrmax1 = -1.0f / fmaxf(bmax1, 1e-30f);
        float rm20 = rmin0 * LOG2E, rm21 = rmin1 * LOG2E;
        float nx20 = nrmax0 * LOG2E, nx21 = nrmax1 * LOG2E;
        carrA[lane] = make_float4(rm20, rm21, nx20, nx21);
        carrB[lane] = make_float4(-rm20 * Mm0, -rm21 * Mm1, nx20 * Mg0, nx21 * Mg1);
    }
    __syncthreads();

    float4 cA = carrA[lane], cB = carrB[lane];

    float4 accS = make_float4(0.f, 0.f, 0.f, 0.f);
    #pragma unroll
    for (int z = 0; z < 8; ++z) {
        float4 q = mrow[z];
        float wv = wreg[z];
        accS.x = fmaf(wv, __builtin_amdgcn_exp2f(fmaf(q.x, cA.x, cB.x)), accS.x);
        accS.y = fmaf(wv, __builtin_amdgcn_exp2f(fmaf(q.y, cA.z, cB.z)), accS.y);
        accS.z = fmaf(wv, __builtin_amdgcn_exp2f(fmaf(q.z, cA.y, cB.y)), accS.z);
        accS.w = fmaf(wv, __builtin_amdgcn_exp2f(fmaf(q.w, cA.w, cB.w)), accS.w);
    }
    red[w][lane] = accS;
    __syncthreads();

    if (tid < 64) {
        float4 S = red[0][lane];
        #pragma unroll
        for (int ww = 1; ww < 8; ++ww) {
            float4 t = red[ww][lane];
            S.x += t.x; S.y += t.y; S.z += t.z; S.w += t.w;
        }
        const float S10 = fmaxf(S.x, 1e-35f);
        const float S20 = fmaxf(S.y, 1e-35f);
        const float S11 = fmaxf(S.z, 1e-35f);
        const float S21 = fmaxf(S.w, 1e-35f);
        const int idx = c * DD + 2 * lane;
        float v10 = bmin0 * fmaf(rmin0, Mm0, __logf(S10));
        float v11 = bmin1 * fmaf(rmin1, Mm1, __logf(S11));
        float v20 = -bmax0 * fmaf(-nrmax0, Mg0, __logf(S20));
        float v21 = -bmax1 * fmaf(-nrmax1, Mg1, __logf(S21));
        *(float2*)(out + 32768 + idx)  = make_float2(v10, v11);
        *(float2*)(out + 98304 + idx)  = make_float2(v20, v21);
        *(float2*)(out + 163840 + idx) = make_float2(bmin0, bmin1);
        *(float2*)(out + 229376 + idx) = make_float2(bmax0, bmax1);
        *(float4*)(mu2_1 + idx) = make_float4(v10, v20, v11, v21);
        *(float4*)(bb2_1 + idx) = make_float4(bmin0, bmax0, bmin1, bmax1);
    }
}

// Level-2 DENSE, R33 (= R31 verbatim, best measured 41.6us / 113.8 total):
// in-load-order consumption (compute starts at first-arrival vmcnt, +3us vs
// nested-fmaf R26). Closed axes: register pipelining (R1 sink, R2/R7 spill),
// TLP dim-split (R8 spill, R9 duplicated-gumbel regression), async LDS staging
// (R12: LDS latency + wait serialization > L2 latency hidden, +4.6us).
// Remaining 41.6us is a latency-bound L2 stream ~2x above its ~21us VALU floor;
// L2 BW at 36% of ceiling (not BW-bound). Practical floor for this toolchain.
__global__ __launch_bounds__(512, 4)
void k_level2d(const float* __restrict__ logits, const float* __restrict__ u,
               const float2* __restrict__ bb2, const float2* __restrict__ mu2,
               const float4* __restrict__ pmaxf,
               float* __restrict__ o_mu_min, float* __restrict__ o_mu_max,
               float* __restrict__ o_b_min, float* __restrict__ o_b_max) {
    constexpr int P = 512, TC = 4;
    __shared__ __align__(16) float wsh[P][TC];
    __shared__ int npres[TC];
    __shared__ float4 red[8][TC][64];
    __shared__ float4 carrA[TC][64], carrB[TC][64];
    const int tid = threadIdx.x;
    const int w = tid >> 6;
    const int lane = tid & 63;
    const int c0 = blockIdx.x * TC;
    if (tid < TC) npres[tid] = 0;
    __syncthreads();

    #pragma unroll
    for (int it = 0; it < TC; ++it) {
        int idx = (c0 + it) * P + tid;
        float uu = u[idx] + 1e-10f;
        float g = -__logf(-__logf(uu) + 1e-10f);
        bool pres = (logits[idx] + g) > 0.0f;
        wsh[tid][it] = pres ? 1.0f : 1e-10f;
        unsigned long long m = __ballot(pres);
        if (lane == 0) atomicAdd(&npres[it], (int)__popcll(m));
    }
    __syncthreads();

    const unsigned lb = (unsigned)(lane << 4);
    const char* bbc = (const char*)bb2 + (unsigned)(w * 64) * 1024u + lb;
    const char* muc = (const char*)mu2 + (unsigned)(w * 64) * 1024u + lb;
    const int p0 = w * 64;

    // ---------------- pass 1: weighted beta sums (in-load-order consume) --------
    float4 accB[TC];
    #pragma unroll
    for (int j = 0; j < TC; ++j) accB[j] = make_float4(0.f, 0.f, 0.f, 0.f);
    for (int z = 0; z < 64; z += 4) {
        float4 q0 = *(const float4*)(bbc + (unsigned)(z + 0) * 1024u);
        float4 q1 = *(const float4*)(bbc + (unsigned)(z + 1) * 1024u);
        float4 q2 = *(const float4*)(bbc + (unsigned)(z + 2) * 1024u);
        float4 q3 = *(const float4*)(bbc + (unsigned)(z + 3) * 1024u);
        float4 w0 = *(const float4*)wsh[p0 + z + 0];
        float4 w1 = *(const float4*)wsh[p0 + z + 1];
        float4 w2 = *(const float4*)wsh[p0 + z + 2];
        float4 w3 = *(const float4*)wsh[p0 + z + 3];
        const float* wf0 = (const float*)&w0;
        const float* wf1 = (const float*)&w1;
        const float* wf2 = (const float*)&w2;
        const float* wf3 = (const float*)&w3;
        #pragma unroll
        for (int j = 0; j < TC; ++j) {
            accB[j].x = fmaf(wf0[j], q0.x, accB[j].x);
            accB[j].y = fmaf(wf0[j], q0.y, accB[j].y);
            accB[j].z = fmaf(wf0[j], q0.z, accB[j].z);
            accB[j].w = fmaf(wf0[j], q0.w, accB[j].w);
        }
        #pragma unroll
        for (int j = 0; j < TC; ++j) {
            accB[j].x = fmaf(wf1[j], q1.x, accB[j].x);
            accB[j].y = fmaf(wf1[j], q1.y, accB[j].y);
            accB[j].z = fmaf(wf1[j], q1.z, accB[j].z);
            accB[j].w = fmaf(wf1[j], q1.w, accB[j].w);
        }
        #pragma unroll
        for (int j = 0; j < TC; ++j) {
            accB[j].x = fmaf(wf2[j], q2.x, accB[j].x);
            accB[j].y = fmaf(wf2[j], q2.y, accB[j].y);
            accB[j].z = fmaf(wf2[j], q2.z, accB[j].z);
            accB[j].w = fmaf(wf2[j], q2.w, accB[j].w);
        }
        #pragma unroll
        for (int j = 0; j < TC; ++j) {
            accB[j].x = fmaf(wf3[j], q3.x, accB[j].x);
            accB[j].y = fmaf(wf3[j], q3.y, accB[j].y);
            accB[j].z = fmaf(wf3[j], q3.z, accB[j].z);
            accB[j].w = fmaf(wf3[j], q3.w, accB[j].w);
        }
    }
    #pragma unroll
    for (int j = 0; j < TC; ++j) red[w][j][lane] = accB[j];
    __syncthreads();

    float bmin0, bmax0, bmin1, bmax1, rmin0, rmin1, nrmax0, nrmax1, Mm0, Mm1, Mg0, Mg1;
    const int rj = tid >> 6;
    if (tid < 256) {
        float4 S = red[0][rj][lane];
        #pragma unroll
        for (int ww = 1; ww < 8; ++ww) {
            float4 t = red[ww][rj][lane];
            S.x += t.x; S.y += t.y; S.z += t.z; S.w += t.w;
        }
        float4 km = pmaxf[lane];
        Mm0 = km.x; Mg0 = km.y; Mm1 = km.z; Mg1 = km.w;
        const float wsv = (float)npres[rj] + 1e-10f;
        bmin0 = S.x / wsv; bmax0 = S.y / wsv; bmin1 = S.z / wsv; bmax1 = S.w / wsv;
        rmin0 = 1.0f / fmaxf(bmin0, 1e-30f);
        rmin1 = 1.0f / fmaxf(bmin1, 1e-30f);
        nrmax0 = -1.0f / fmaxf(bmax0, 1e-30f);
        nrmax1 = -1.0f / fmaxf(bmax1, 1e-30f);
        float rm20 = rmin0 * LOG2E, rm21 = rmin1 * LOG2E;
        float nx20 = nrmax0 * LOG2E, nx21 = nrmax1 * LOG2E;
        carrA[rj][lane] = make_float4(rm20, rm21, nx20, nx21);
        carrB[rj][lane] = make_float4(-rm20 * Mm0, -rm21 * Mm1, nx20 * Mg0, nx21 * Mg1);
    }
    __syncthreads();

    float4 cA[TC], cB[TC];
    #pragma unroll
    for (int j = 0; j < TC; ++j) { cA[j] = carrA[j][lane]; cB[j] = carrB[j][lane]; }

    // ---------------- pass 2: exp accumulation (already in load order) ----------
    float4 accS[TC];
    #pragma unroll
    for (int j = 0; j < TC; ++j) accS[j] = make_float4(0.f, 0.f, 0.f, 0.f);
    for (int z = 0; z < 64; z += 4) {
        float4 q0 = *(const float4*)(muc + (unsigned)(z + 0) * 1024u);
        float4 q1 = *(const float4*)(muc + (unsigned)(z + 1) * 1024u);
        float4 q2 = *(const float4*)(muc + (unsigned)(z + 2) * 1024u);
        float4 q3 = *(const float4*)(muc + (unsigned)(z + 3) * 1024u);
        float4 w0 = *(const float4*)wsh[p0 + z + 0];
        float4 w1 = *(const float4*)wsh[p0 + z + 1];
        float4 w2 = *(const float4*)wsh[p0 + z + 2];
        float4 w3 = *(const float4*)wsh[p0 + z + 3];
        const float* wf0 = (const float*)&w0;
        const float* wf1 = (const float*)&w1;
        const float* wf2 = (const float*)&w2;
        const float* wf3 = (const float*)&w3;
        #pragma unroll
        for (int j = 0; j < TC; ++j) {
            if (wf0[j] > 0.5f) {
                accS[j].x += __builtin_amdgcn_exp2f(fmaf(q0.x, cA[j].x, cB[j].x));
                accS[j].y += __builtin_amdgcn_exp2f(fmaf(q0.y, cA[j].z, cB[j].z));
                accS[j].z += __builtin_amdgcn_exp2f(fmaf(q0.z, cA[j].y, cB[j].y));
                accS[j].w += __builtin_amdgcn_exp2f(fmaf(q0.w, cA[j].w, cB[j].w));
            }
            if (wf1[j] > 0.5f) {
                accS[j].x += __builtin_amdgcn_exp2f(fmaf(q1.x, cA[j].x, cB[j].x));
                accS[j].y += __builtin_amdgcn_exp2f(fmaf(q1.y, cA[j].z, cB[j].z));
                accS[j].z += __builtin_amdgcn_exp2f(fmaf(q1.z, cA[j].y, cB[j].y));
                accS[j].w += __builtin_amdgcn_exp2f(fmaf(q1.w, cA[j].w, cB[j].w));
            }
            if (wf2[j] > 0.5f) {
                accS[j].x += __builtin_amdgcn_exp2f(fmaf(q2.x, cA[j].x, cB[j].x));
                accS[j].y += __builtin_amdgcn_exp2f(fmaf(q2.y, cA[j].z, cB[j].z));
                accS[j].z += __builtin_amdgcn_exp2f(fmaf(q2.z, cA[j].y, cB[j].y));
                accS[j].w += __builtin_amdgcn_exp2f(fmaf(q2.w, cA[j].w, cB[j].w));
            }
            if (wf3[j] > 0.5f) {
                accS[j].x += __builtin_amdgcn_exp2f(fmaf(q3.x, cA[j].x, cB[j].x));
                accS[j].y += __builtin_amdgcn_exp2f(fmaf(q3.y, cA[j].z, cB[j].z));
                accS[j].z += __builtin_amdgcn_exp2f(fmaf(q3.z, cA[j].y, cB[j].y));
                accS[j].w += __builtin_amdgcn_exp2f(fmaf(q3.w, cA[j].w, cB[j].w));
            }
        }
    }
    #pragma unroll
    for (int j = 0; j < TC; ++j) red[w][j][lane] = accS[j];
    __syncthreads();

    if (tid < 256) {
        float4 S = red[0][rj][lane];
        #pragma unroll
        for (int ww = 1; ww < 8; ++ww) {
            float4 t = red[ww][rj][lane];
            S.x += t.x; S.y += t.y; S.z += t.z; S.w += t.w;
        }
        const float S10 = fmaxf(S.x, 1e-35f);
        const float S20 = fmaxf(S.y, 1e-35f);
        const float S11 = fmaxf(S.z, 1e-35f);
        const float S21 = fmaxf(S.w, 1e-35f);
        const int idx = (c0 + rj) * DD + 2 * lane;
        float v10 = bmin0 * fmaf(rmin0, Mm0, __logf(S10));
        float v11 = bmin1 * fmaf(rmin1, Mm1, __logf(S11));
        float v20 = -bmax0 * fmaf(-nrmax0, Mg0, __logf(S20));
        float v21 = -bmax1 * fmaf(-nrmax1, Mg1, __logf(S21));
        *(float2*)(o_mu_min + idx) = make_float2(v10, v11);
        *(float2*)(o_mu_max + idx) = make_float2(v20, v21);
        *(float2*)(o_b_min + idx)  = make_float2(bmin0, bmin1);
        *(float2*)(o_b_max + idx)  = make_float2(bmax0, bmax1);
    }
}

extern "C" void kernel_launch(void* const* d_in, const int* in_sizes, int n_in,
                              void* d_out, int out_size, void* d_ws, size_t ws_size,
                              hipStream_t stream) {
    const float* mu_min0  = (const float*)d_in[0];
    const float* mu_max0  = (const float*)d_in[1];
    const float* braw_min = (const float*)d_in[2];
    const float* braw_max = (const float*)d_in[3];
    const float* adj0     = (const float*)d_in[4];   // (512, 64)
    const float* adj1     = (const float*)d_in[5];   // (2048, 512)
    const float* u0       = (const float*)d_in[6];   // (1, 512, 64)
    const float* u1       = (const float*)d_in[7];   // (1, 2048, 512)
    float* out = (float*)d_out;
    float* ws = (float*)d_ws;

    float4* pmaxf = (float4*)ws;                    // 64 float4 = 1 KB
    float2* mu2_1 = (float2*)(ws + 256);            // 512*128 float2 = 512 KB
    float2* bb2_1 = mu2_1 + 512 * DD;               // 512 KB

    // out offsets (f32): 0:mu_min0 8192:mu_max0 16384:bmin0 24576:bmax0
    // 32768:mu_min1 98304:mu_max1 163840:b_min1 229376:b_max1 (each 65536)
    // 294912:mu_min2 557056:mu_max2 819200:b_min2 1081344:b_max2 (each 262144)

    k_lvl1<<<dim3(512), dim3(512), 0, stream>>>(
        mu_min0, mu_max0, braw_min, braw_max, adj0, u0,
        out, mu2_1, bb2_1, pmaxf);

    k_level2d<<<dim3(512), dim3(512), 0, stream>>>(
        adj1, u1, bb2_1, mu2_1, pmaxf,
        out + 294912, out + 557056, out + 819200, out + 1081344);
}